// Round 1
// baseline (112.056 us; speedup 1.0000x reference)
//
#include <hip/hip_runtime.h>
#include <math.h>

#define NQ 8
#define NS 256      // 2^NQ amplitudes
#define NK 16       // encoded subspace (qubits 0-3)
#define NL 3

// ---------------------------------------------------------------------------
// Kernel S: one block. Simulates the fixed (params-dependent) part of the
// circuit on the 16 basis vectors, builds R_j[k][l] (j=0..3), zeroes the
// 32-binned double accumulators used for batch-norm statistics.
// ---------------------------------------------------------------------------
__global__ __launch_bounds__(256) void setup_kernel(
    const float* __restrict__ params,   // [3][8]
    const float* __restrict__ W,        // [4][8]
    float* __restrict__ R_ws,           // [4][256]  (j, k*16+l)
    double* __restrict__ acc)           // [32][8]
{
    __shared__ float M[NS * NK];    // M[s][k]
    __shared__ float TS[NS * 4];    // TS[s][j] = sum_w W[j][w]*sign_w(s)
    const int t = threadIdx.x;

    // zero BN accumulator bins (32 bins x 8 doubles = 256)
    acc[t] = 0.0;

    // init M to basis columns: state k has amplitude 1 at flat index k*16
    #pragma unroll
    for (int k = 0; k < NK; ++k) M[t * NK + k] = 0.f;
    if ((t & 15) == 0) M[t * NK + (t >> 4)] = 1.f;

    const int pair = t & 127;   // RY pair index
    const int kh   = t >> 7;    // which 8-wide half of the 16 columns

    for (int layer = 0; layer < NL; ++layer) {
        // 8 RY gates
        for (int q = 0; q < NQ; ++q) {
            __syncthreads();
            const float th = params[layer * 8 + q] * 0.5f;
            const float c  = __cosf(th);
            const float sn = __sinf(th);
            const int m   = 1 << (7 - q);
            const int low = pair & (m - 1);
            const int s0  = ((pair ^ low) << 1) | low;  // bit q = 0
            const int s1  = s0 | m;                     // bit q = 1
            float v0[8], v1[8];
            #pragma unroll
            for (int k = 0; k < 8; ++k) {
                v0[k] = M[s0 * NK + kh * 8 + k];
                v1[k] = M[s1 * NK + kh * 8 + k];
            }
            #pragma unroll
            for (int k = 0; k < 8; ++k) {
                float n0 = c * v0[k] - sn * v1[k];
                float n1 = sn * v0[k] + c * v1[k];
                M[s0 * NK + kh * 8 + k] = n0;
                M[s1 * NK + kh * 8 + k] = n1;
            }
        }
        // CNOT chain q=0..6 collapsed to one gather permutation:
        // state'[s] = state[c01(c12(...c67(s)))]
        __syncthreads();
        int src = t;
        #pragma unroll
        for (int q = 6; q >= 0; --q) {
            int bit = (src >> (7 - q)) & 1;
            src ^= bit << (6 - q);      // target mask = 1<<(7-(q+1))
        }
        float r[NK];
        #pragma unroll
        for (int k = 0; k < NK; ++k) r[k] = M[src * NK + k];
        __syncthreads();
        #pragma unroll
        for (int k = 0; k < NK; ++k) M[t * NK + k] = r[k];
    }
    __syncthreads();

    // TS[s][j] = sum_w W[j][w] * (bit_w(s) ? -1 : +1)
    {
        const int s = t;
        #pragma unroll
        for (int j = 0; j < 4; ++j) {
            float a = 0.f;
            #pragma unroll
            for (int w = 0; w < 8; ++w) {
                float sign = ((s >> (7 - w)) & 1) ? -1.f : 1.f;
                a += W[j * 8 + w] * sign;
            }
            TS[s * 4 + j] = a;
        }
    }
    __syncthreads();

    // R_j[k][l] = sum_s M[s][k]*M[s][l]*TS[s][j]
    const int k = t >> 4, l = t & 15;
    float r0 = 0.f, r1 = 0.f, r2 = 0.f, r3 = 0.f;
    for (int s = 0; s < NS; ++s) {
        float mk = M[s * NK + k];
        float ml = M[s * NK + l];
        float mm = mk * ml;
        r0 += mm * TS[s * 4 + 0];
        r1 += mm * TS[s * 4 + 1];
        r2 += mm * TS[s * 4 + 2];
        r3 += mm * TS[s * 4 + 3];
    }
    R_ws[0 * 256 + t] = r0;
    R_ws[1 * 256 + t] = r1;
    R_ws[2 * 256 + t] = r2;
    R_ws[3 * 256 + t] = r3;
}

// ---------------------------------------------------------------------------
// Kernel A: pooling + quadratic forms + BN partial sums.
// Block: 256 threads, 64 batch elements. Grid: B/64 blocks.
// ---------------------------------------------------------------------------
__global__ __launch_bounds__(256, 4) void main_kernel(
    const float* __restrict__ x,      // [B][144]
    const float* __restrict__ bvec,   // [4]
    const float* __restrict__ R_ws,   // [4][256]
    float* __restrict__ out_col,      // [4][B]  column-major pre-BN output
    double* __restrict__ acc,         // [32][8]
    int B)
{
    __shared__ float4 tile[2304];     // 64 elements * 36 float4 = 36 KB
    __shared__ float  part[64 * 9];   // per-(element, rowband-part) L/R sums, pad 9

    const int t   = threadIdx.x;
    const int blk = blockIdx.x;

    // ---- stage 64 elements (coalesced float4) ----
    const float4* xg = (const float4*)x + (size_t)blk * 2304;
    #pragma unroll
    for (int i = 0; i < 9; ++i) tile[i * 256 + t] = xg[i * 256 + t];
    __syncthreads();

    // ---- pooling partial sums: thread = (e = t>>2, p = t&3), p = 3-row band ----
    {
        float sl = 0.f, sr = 0.f;
        #pragma unroll
        for (int i = 0; i < 9; ++i) {
            float4 v = tile[t * 9 + i];
            const int mod = i % 3;      // position within a 12-col row
            if (mod == 0)      { sl += v.x + v.y + v.z + v.w; }
            else if (mod == 1) { sl += v.x + v.y; sr += v.z + v.w; }
            else               { sr += v.x + v.y + v.z + v.w; }
        }
        part[(t >> 2) * 9 + (t & 3) * 2 + 0] = sl;
        part[(t >> 2) * 9 + (t & 3) * 2 + 1] = sr;
    }
    __syncthreads();

    // ---- quadratic forms: wave w handles output column p = w for 64 elements ----
    const int e = t & 63;
    const int p = __builtin_amdgcn_readfirstlane(t >> 6);   // wave-uniform column

    const float* pe = &part[e * 9];
    const float k36 = 0.5f / 36.f;                 // mean + theta/2 folded
    float th0 = (pe[0] + pe[2]) * k36;             // quadrant 0 (rows 0-5, cols 0-5)
    float th1 = (pe[1] + pe[3]) * k36;             // quadrant 1 (rows 0-5, cols 6-11)
    float th2 = (pe[4] + pe[6]) * k36;             // quadrant 2
    float th3 = (pe[5] + pe[7]) * k36;             // quadrant 3

    float c0 = __cosf(th0), s0 = __sinf(th0);
    float c1 = __cosf(th1), s1 = __sinf(th1);
    float c2 = __cosf(th2), s2 = __sinf(th2);
    float c3 = __cosf(th3), s3 = __sinf(th3);

    // a[k] = product over qubits 0..3, qubit0 = MSB of k
    float u[4] = { c0 * c1, c0 * s1, s0 * c1, s0 * s1 };
    float v[4] = { c2 * c3, c2 * s3, s2 * c3, s2 * s3 };
    float a[16];
    #pragma unroll
    for (int i = 0; i < 4; ++i)
        #pragma unroll
        for (int j = 0; j < 4; ++j) a[i * 4 + j] = u[i] * v[j];

    // out_p = a^T R_p a + b_p   (R via wave-uniform scalar loads)
    const float* Rp = R_ws + p * 256;
    float o = bvec[p];
    #pragma unroll
    for (int kk = 0; kk < 16; ++kk) {
        float dot = 0.f;
        #pragma unroll
        for (int ll = 0; ll < 16; ++ll) dot = fmaf(Rp[kk * 16 + ll], a[ll], dot);
        o = fmaf(a[kk], dot, o);
    }

    out_col[(size_t)p * B + blk * 64 + e] = o;

    // ---- per-wave reduction for BN stats (all lanes share p) ----
    float s1v = o, s2v = o * o;
    #pragma unroll
    for (int off = 1; off < 64; off <<= 1) {
        s1v += __shfl_xor(s1v, off);
        s2v += __shfl_xor(s2v, off);
    }
    if (e == 0) {
        const int bin = blk & 31;
        atomicAdd(&acc[bin * 8 + p],     (double)s1v);
        atomicAdd(&acc[bin * 8 + 4 + p], (double)s2v);
    }
}

// ---------------------------------------------------------------------------
// Kernel B: finalize batch-norm and write output [B][4].
// ---------------------------------------------------------------------------
__global__ __launch_bounds__(256) void bn_kernel(
    const float* __restrict__ out_col,  // [4][B]
    const double* __restrict__ acc,     // [32][8]
    const float* __restrict__ gamma,
    const float* __restrict__ beta,
    float* __restrict__ outp,           // [B][4]
    int B)
{
    __shared__ float sc[4], sh[4];
    const int t = threadIdx.x;
    if (t < 4) {
        double s = 0.0, s2 = 0.0;
        #pragma unroll
        for (int bin = 0; bin < 32; ++bin) {
            s  += acc[bin * 8 + t];
            s2 += acc[bin * 8 + 4 + t];
        }
        double invB = 1.0 / (double)B;
        double mean = s * invB;
        double var  = s2 * invB - mean * mean;
        float inv   = (float)(1.0 / sqrt(var + 1e-5));
        float g     = gamma[t] * inv;
        sc[t] = g;
        sh[t] = beta[t] - (float)mean * g;
    }
    __syncthreads();

    const int i = blockIdx.x * 256 + t;
    float o0 = out_col[(size_t)0 * B + i];
    float o1 = out_col[(size_t)1 * B + i];
    float o2 = out_col[(size_t)2 * B + i];
    float o3 = out_col[(size_t)3 * B + i];
    float4 r;
    r.x = fmaf(o0, sc[0], sh[0]);
    r.y = fmaf(o1, sc[1], sh[1]);
    r.z = fmaf(o2, sc[2], sh[2]);
    r.w = fmaf(o3, sc[3], sh[3]);
    ((float4*)outp)[i] = r;
}

// ---------------------------------------------------------------------------
extern "C" void kernel_launch(void* const* d_in, const int* in_sizes, int n_in,
                              void* d_out, int out_size, void* d_ws, size_t ws_size,
                              hipStream_t stream)
{
    const float* x      = (const float*)d_in[0];   // [B,1,12,12]
    const float* params = (const float*)d_in[1];   // [3,8]
    const float* W      = (const float*)d_in[2];   // [4,8]
    const float* bvec   = (const float*)d_in[3];   // [4]
    const float* gamma  = (const float*)d_in[4];   // [4]
    const float* beta   = (const float*)d_in[5];   // [4]

    const int B = in_sizes[0] / 144;               // 65536

    float*  R_ws    = (float*)d_ws;                           // 4 KB
    double* acc     = (double*)((char*)d_ws + 4096);          // 2 KB
    float*  out_col = (float*)((char*)d_ws + 8192);           // 4*B floats

    float* outp = (float*)d_out;

    setup_kernel<<<1, 256, 0, stream>>>(params, W, R_ws, acc);
    main_kernel<<<B / 64, 256, 0, stream>>>(x, bvec, R_ws, out_col, acc, B);
    bn_kernel<<<B / 256, 256, 0, stream>>>(out_col, acc, gamma, beta, outp, B);
}

// Round 2
// 109.954 us; speedup vs baseline: 1.0191x; 1.0191x over previous
//
#include <hip/hip_runtime.h>
#include <math.h>

#define NQ 8
#define NS 256      // 2^NQ amplitudes
#define NK 16       // encoded subspace (qubits 0-3)
#define NL 3
#define MTS 260     // padded transposed row stride (16B aligned, 2-way bank alias = free)

// ---------------------------------------------------------------------------
// Kernel S: 4 blocks (one per output column j). Each simulates the fixed
// circuit on the 16 basis columns, then builds R_j[k][l] via a float4
// LDS dot-product with TS_j folded into one operand.
// Block 0 additionally zeroes the BN accumulator bins.
// ---------------------------------------------------------------------------
__global__ __launch_bounds__(256) void setup_kernel(
    const float* __restrict__ params,   // [3][8]
    const float* __restrict__ W,        // [4][8]
    float* __restrict__ R_ws,           // [4][256]  (j, k*16+l)
    double* __restrict__ acc)           // [32][8]
{
    __shared__ float M[NS * NK];      // M[s][k]          16 KB
    __shared__ float MT[NK * MTS];    // MT[k][s]         16.6 KB
    __shared__ float PT[NK * MTS];    // PT[k][s]=ts*M    16.6 KB
    const int t = threadIdx.x;
    const int j = blockIdx.x;

    if (j == 0) acc[t] = 0.0;   // zero BN accumulator bins (32 x 8 doubles)

    // init M to basis columns: state k has amplitude 1 at flat index k*16
    #pragma unroll
    for (int k = 0; k < NK; ++k) M[t * NK + k] = 0.f;
    if ((t & 15) == 0) M[t * NK + (t >> 4)] = 1.f;

    const int pair = t & 127;   // RY pair index
    const int kh   = t >> 7;    // which 8-wide half of the 16 columns

    for (int layer = 0; layer < NL; ++layer) {
        // 8 RY gates
        for (int q = 0; q < NQ; ++q) {
            __syncthreads();
            const float th = params[layer * 8 + q] * 0.5f;
            const float c  = __cosf(th);
            const float sn = __sinf(th);
            const int m   = 1 << (7 - q);
            const int low = pair & (m - 1);
            const int s0  = ((pair ^ low) << 1) | low;  // bit q = 0
            const int s1  = s0 | m;                     // bit q = 1
            float v0[8], v1[8];
            #pragma unroll
            for (int k = 0; k < 8; ++k) {
                v0[k] = M[s0 * NK + kh * 8 + k];
                v1[k] = M[s1 * NK + kh * 8 + k];
            }
            #pragma unroll
            for (int k = 0; k < 8; ++k) {
                float n0 = c * v0[k] - sn * v1[k];
                float n1 = sn * v0[k] + c * v1[k];
                M[s0 * NK + kh * 8 + k] = n0;
                M[s1 * NK + kh * 8 + k] = n1;
            }
        }
        // CNOT chain q=0..6 collapsed to one gather permutation
        __syncthreads();
        int src = t;
        #pragma unroll
        for (int q = 6; q >= 0; --q) {
            int bit = (src >> (7 - q)) & 1;
            src ^= bit << (6 - q);
        }
        float r[NK];
        #pragma unroll
        for (int k = 0; k < NK; ++k) r[k] = M[src * NK + k];
        __syncthreads();
        #pragma unroll
        for (int k = 0; k < NK; ++k) M[t * NK + k] = r[k];
    }
    __syncthreads();

    // ts_j[s] = sum_w W[j][w] * (bit_w(s) ? -1 : +1); transpose + fold
    {
        const int s = t;
        float ts = 0.f;
        #pragma unroll
        for (int w = 0; w < 8; ++w) {
            float sign = ((s >> (7 - w)) & 1) ? -1.f : 1.f;
            ts += W[j * 8 + w] * sign;
        }
        #pragma unroll
        for (int k = 0; k < NK; ++k) {
            float m = M[s * NK + k];
            MT[k * MTS + s] = m;
            PT[k * MTS + s] = ts * m;
        }
    }
    __syncthreads();

    // R_j[k][l] = sum_s MT[k][s] * PT[l][s]   (float4 over s)
    const int k = t >> 4, l = t & 15;
    const float4* mk4 = (const float4*)&MT[k * MTS];
    const float4* pl4 = (const float4*)&PT[l * MTS];
    float r = 0.f;
    #pragma unroll 8
    for (int i = 0; i < NS / 4; ++i) {
        float4 a = mk4[i];
        float4 b = pl4[i];
        r += a.x * b.x + a.y * b.y + a.z * b.z + a.w * b.w;
    }
    R_ws[j * 256 + t] = r;
}

// ---------------------------------------------------------------------------
// Kernel A: pooling + quadratic forms + BN partial sums.
// Block: 256 threads, 64 batch elements. Grid: B/64 blocks.
// ---------------------------------------------------------------------------
__global__ __launch_bounds__(256, 4) void main_kernel(
    const float* __restrict__ x,      // [B][144]
    const float* __restrict__ bvec,   // [4]
    const float* __restrict__ R_ws,   // [4][256]
    float* __restrict__ out_col,      // [4][B]  column-major pre-BN output
    double* __restrict__ acc,         // [32][8]
    int B)
{
    __shared__ float4 tile[2304];     // 64 elements * 36 float4 = 36 KB
    __shared__ float  part[64 * 9];   // per-(element, band-part) L/R sums, pad 9

    const int t   = threadIdx.x;
    const int blk = blockIdx.x;

    // ---- stage 64 elements (coalesced float4) ----
    const float4* xg = (const float4*)x + (size_t)blk * 2304;
    #pragma unroll
    for (int i = 0; i < 9; ++i) tile[i * 256 + t] = xg[i * 256 + t];
    __syncthreads();

    // ---- pooling partial sums: thread = (e = t>>2, p = t&3), p = 3-row band ----
    {
        float sl = 0.f, sr = 0.f;
        #pragma unroll
        for (int i = 0; i < 9; ++i) {
            float4 v = tile[t * 9 + i];
            const int mod = i % 3;      // position within a 12-col row
            if (mod == 0)      { sl += v.x + v.y + v.z + v.w; }
            else if (mod == 1) { sl += v.x + v.y; sr += v.z + v.w; }
            else               { sr += v.x + v.y + v.z + v.w; }
        }
        part[(t >> 2) * 9 + (t & 3) * 2 + 0] = sl;
        part[(t >> 2) * 9 + (t & 3) * 2 + 1] = sr;
    }
    __syncthreads();

    // ---- quadratic forms: wave w handles output column p = w for 64 elements ----
    const int e = t & 63;
    const int p = __builtin_amdgcn_readfirstlane(t >> 6);   // wave-uniform column

    const float* pe = &part[e * 9];
    const float k36 = 0.5f / 36.f;                 // mean + theta/2 folded
    float th0 = (pe[0] + pe[2]) * k36;             // quadrant 0 (rows 0-5, cols 0-5)
    float th1 = (pe[1] + pe[3]) * k36;             // quadrant 1 (rows 0-5, cols 6-11)
    float th2 = (pe[4] + pe[6]) * k36;             // quadrant 2
    float th3 = (pe[5] + pe[7]) * k36;             // quadrant 3

    float c0 = __cosf(th0), s0 = __sinf(th0);
    float c1 = __cosf(th1), s1 = __sinf(th1);
    float c2 = __cosf(th2), s2 = __sinf(th2);
    float c3 = __cosf(th3), s3 = __sinf(th3);

    // a[k] = product over qubits 0..3, qubit0 = MSB of k
    float u[4] = { c0 * c1, c0 * s1, s0 * c1, s0 * s1 };
    float v[4] = { c2 * c3, c2 * s3, s2 * c3, s2 * s3 };
    float a[16];
    #pragma unroll
    for (int i = 0; i < 4; ++i)
        #pragma unroll
        for (int jj = 0; jj < 4; ++jj) a[i * 4 + jj] = u[i] * v[jj];

    // out_p = a^T R_p a + b_p   (R via wave-uniform scalar loads)
    const float* Rp = R_ws + p * 256;
    float o = bvec[p];
    #pragma unroll
    for (int kk = 0; kk < 16; ++kk) {
        float dot = 0.f;
        #pragma unroll
        for (int ll = 0; ll < 16; ++ll) dot = fmaf(Rp[kk * 16 + ll], a[ll], dot);
        o = fmaf(a[kk], dot, o);
    }

    out_col[(size_t)p * B + blk * 64 + e] = o;

    // ---- per-wave reduction for BN stats (all lanes share p) ----
    float s1v = o, s2v = o * o;
    #pragma unroll
    for (int off = 1; off < 64; off <<= 1) {
        s1v += __shfl_xor(s1v, off);
        s2v += __shfl_xor(s2v, off);
    }
    if (e == 0) {
        const int bin = blk & 31;
        atomicAdd(&acc[bin * 8 + p],     (double)s1v);
        atomicAdd(&acc[bin * 8 + 4 + p], (double)s2v);
    }
}

// ---------------------------------------------------------------------------
// Kernel B: finalize batch-norm and write output [B][4].
// ---------------------------------------------------------------------------
__global__ __launch_bounds__(256) void bn_kernel(
    const float* __restrict__ out_col,  // [4][B]
    const double* __restrict__ acc,     // [32][8]
    const float* __restrict__ gamma,
    const float* __restrict__ beta,
    float* __restrict__ outp,           // [B][4]
    int B)
{
    __shared__ float sc[4], sh[4];
    const int t = threadIdx.x;
    if (t < 4) {
        double s = 0.0, s2 = 0.0;
        #pragma unroll
        for (int bin = 0; bin < 32; ++bin) {
            s  += acc[bin * 8 + t];
            s2 += acc[bin * 8 + 4 + t];
        }
        double invB = 1.0 / (double)B;
        double mean = s * invB;
        double var  = s2 * invB - mean * mean;
        float inv   = (float)(1.0 / sqrt(var + 1e-5));
        float g     = gamma[t] * inv;
        sc[t] = g;
        sh[t] = beta[t] - (float)mean * g;
    }
    __syncthreads();

    const int i = blockIdx.x * 256 + t;
    float o0 = out_col[(size_t)0 * B + i];
    float o1 = out_col[(size_t)1 * B + i];
    float o2 = out_col[(size_t)2 * B + i];
    float o3 = out_col[(size_t)3 * B + i];
    float4 r;
    r.x = fmaf(o0, sc[0], sh[0]);
    r.y = fmaf(o1, sc[1], sh[1]);
    r.z = fmaf(o2, sc[2], sh[2]);
    r.w = fmaf(o3, sc[3], sh[3]);
    ((float4*)outp)[i] = r;
}

// ---------------------------------------------------------------------------
extern "C" void kernel_launch(void* const* d_in, const int* in_sizes, int n_in,
                              void* d_out, int out_size, void* d_ws, size_t ws_size,
                              hipStream_t stream)
{
    const float* x      = (const float*)d_in[0];   // [B,1,12,12]
    const float* params = (const float*)d_in[1];   // [3,8]
    const float* W      = (const float*)d_in[2];   // [4,8]
    const float* bvec   = (const float*)d_in[3];   // [4]
    const float* gamma  = (const float*)d_in[4];   // [4]
    const float* beta   = (const float*)d_in[5];   // [4]

    const int B = in_sizes[0] / 144;               // 65536

    float*  R_ws    = (float*)d_ws;                           // 4 KB
    double* acc     = (double*)((char*)d_ws + 4096);          // 2 KB
    float*  out_col = (float*)((char*)d_ws + 8192);           // 4*B floats

    float* outp = (float*)d_out;

    setup_kernel<<<4, 256, 0, stream>>>(params, W, R_ws, acc);
    main_kernel<<<B / 64, 256, 0, stream>>>(x, bvec, R_ws, out_col, acc, B);
    bn_kernel<<<B / 256, 256, 0, stream>>>(out_col, acc, gamma, beta, outp, B);
}

// Round 3
// 103.852 us; speedup vs baseline: 1.0790x; 1.0588x over previous
//
#include <hip/hip_runtime.h>
#include <math.h>

#define NQ 8
#define NS 256      // 2^NQ amplitudes
#define NK 16       // encoded subspace (qubits 0-3)
#define NL 3
#define XS 20       // exchange-buffer row stride in words (16 + 4 pad -> conflict-free)
#define MTS 260     // transposed row stride (16B aligned, benign aliasing)

// ---------------------------------------------------------------------------
// Kernel S: 4 blocks (one per output column j). Register-resident gate sim:
// thread t owns state s=t's 16-column row in VGPRs. In-wave gates (mask<=32)
// exchange partners via __shfl_xor; q=0,1 and the CNOT permutation go through
// a padded LDS exchange buffer. Then R_j[k][l] via float4 LDS dot-product.
// Block 0 additionally zeroes the BN accumulator bins.
// ---------------------------------------------------------------------------
__global__ __launch_bounds__(256) void setup_kernel(
    const float* __restrict__ params,   // [3][8]
    const float* __restrict__ W,        // [4][8]
    float* __restrict__ R_ws,           // [4][256]  (j, k*16+l)
    double* __restrict__ acc)           // [32][8]
{
    __shared__ float X[NS * XS];      // 20 KB exchange buffer
    __shared__ float MT[NK * MTS];    // MT[k][s]  16.6 KB
    __shared__ float PT[NK * MTS];    // PT[k][s] = ts*M  16.6 KB
    const int t = threadIdx.x;
    const int j = blockIdx.x;

    if (j == 0) acc[t] = 0.0;   // zero BN accumulator bins (32 x 8 doubles)

    // thread t = state s; m[k] = amplitude of state t in basis column k.
    // Column k starts as |k> on qubits 0-3, |0> on 4-7 => flat index k*16.
    float m[NK];
    #pragma unroll
    for (int k = 0; k < NK; ++k) m[k] = 0.f;
    if ((t & 15) == 0) m[t >> 4] = 1.f;

    for (int layer = 0; layer < NL; ++layer) {
        // 8 RY gates, qubit q: partner = t ^ (1<<(7-q))
        for (int q = 0; q < NQ; ++q) {
            const float th = params[layer * 8 + q] * 0.5f;
            const float c  = __cosf(th);
            const float sn = __sinf(th);
            const int mask = 1 << (7 - q);
            const float ss = (t & mask) ? sn : -sn;  // n0 = c*v0 - s*v1 ; n1 = s*v0 + c*v1
            float p[NK];
            if (mask >= 64) {
                // cross-wave: LDS round trip
                __syncthreads();
                #pragma unroll
                for (int k = 0; k < NK; k += 4)
                    *(float4*)&X[t * XS + k] = make_float4(m[k], m[k+1], m[k+2], m[k+3]);
                __syncthreads();
                const int pt = t ^ mask;
                #pragma unroll
                for (int k = 0; k < NK; k += 4) {
                    float4 v = *(const float4*)&X[pt * XS + k];
                    p[k] = v.x; p[k+1] = v.y; p[k+2] = v.z; p[k+3] = v.w;
                }
            } else {
                #pragma unroll
                for (int k = 0; k < NK; ++k) p[k] = __shfl_xor(m[k], mask);
            }
            #pragma unroll
            for (int k = 0; k < NK; ++k) m[k] = fmaf(ss, p[k], c * m[k]);
        }
        // CNOT chain q=0..6 collapsed to one gather permutation
        int src = t;
        #pragma unroll
        for (int q = 6; q >= 0; --q) {
            int bit = (src >> (7 - q)) & 1;
            src ^= bit << (6 - q);
        }
        __syncthreads();
        #pragma unroll
        for (int k = 0; k < NK; k += 4)
            *(float4*)&X[t * XS + k] = make_float4(m[k], m[k+1], m[k+2], m[k+3]);
        __syncthreads();
        #pragma unroll
        for (int k = 0; k < NK; k += 4) {
            float4 v = *(const float4*)&X[src * XS + k];
            m[k] = v.x; m[k+1] = v.y; m[k+2] = v.z; m[k+3] = v.w;
        }
    }

    // ts_j[s] = sum_w W[j][w] * (bit_w(s) ? -1 : +1)
    float ts = 0.f;
    #pragma unroll
    for (int w = 0; w < 8; ++w) {
        float sign = ((t >> (7 - w)) & 1) ? -1.f : 1.f;
        ts += W[j * 8 + w] * sign;
    }

    // write transposed M and ts-folded M (conflict-free: s = lane)
    #pragma unroll
    for (int k = 0; k < NK; ++k) {
        MT[k * MTS + t] = m[k];
        PT[k * MTS + t] = ts * m[k];
    }
    __syncthreads();

    // R_j[k][l] = sum_s MT[k][s] * PT[l][s]   (float4 over s)
    const int k = t >> 4, l = t & 15;
    const float4* mk4 = (const float4*)&MT[k * MTS];
    const float4* pl4 = (const float4*)&PT[l * MTS];
    float r = 0.f;
    #pragma unroll 8
    for (int i = 0; i < NS / 4; ++i) {
        float4 a = mk4[i];
        float4 b = pl4[i];
        r = fmaf(a.x, b.x, r);
        r = fmaf(a.y, b.y, r);
        r = fmaf(a.z, b.z, r);
        r = fmaf(a.w, b.w, r);
    }
    R_ws[j * 256 + t] = r;
}

// ---------------------------------------------------------------------------
// Kernel A: pooling + quadratic forms + BN partial sums.
// Block: 256 threads, 64 batch elements. Grid: B/64 blocks.
// ---------------------------------------------------------------------------
__global__ __launch_bounds__(256, 4) void main_kernel(
    const float* __restrict__ x,      // [B][144]
    const float* __restrict__ bvec,   // [4]
    const float* __restrict__ R_ws,   // [4][256]
    float* __restrict__ out_col,      // [4][B]  column-major pre-BN output
    double* __restrict__ acc,         // [32][8]
    int B)
{
    __shared__ float4 tile[2304];     // 64 elements * 36 float4 = 36 KB
    __shared__ float  part[64 * 9];   // per-(element, band-part) L/R sums, pad 9

    const int t   = threadIdx.x;
    const int blk = blockIdx.x;

    // ---- stage 64 elements (coalesced float4) ----
    const float4* xg = (const float4*)x + (size_t)blk * 2304;
    #pragma unroll
    for (int i = 0; i < 9; ++i) tile[i * 256 + t] = xg[i * 256 + t];
    __syncthreads();

    // ---- pooling partial sums: thread = (e = t>>2, p = t&3), p = 3-row band ----
    {
        float sl = 0.f, sr = 0.f;
        #pragma unroll
        for (int i = 0; i < 9; ++i) {
            float4 v = tile[t * 9 + i];
            const int mod = i % 3;      // position within a 12-col row
            if (mod == 0)      { sl += v.x + v.y + v.z + v.w; }
            else if (mod == 1) { sl += v.x + v.y; sr += v.z + v.w; }
            else               { sr += v.x + v.y + v.z + v.w; }
        }
        part[(t >> 2) * 9 + (t & 3) * 2 + 0] = sl;
        part[(t >> 2) * 9 + (t & 3) * 2 + 1] = sr;
    }
    __syncthreads();

    // ---- quadratic forms: wave w handles output column p = w for 64 elements ----
    const int e = t & 63;
    const int p = __builtin_amdgcn_readfirstlane(t >> 6);   // wave-uniform column

    const float* pe = &part[e * 9];
    const float k36 = 0.5f / 36.f;                 // mean + theta/2 folded
    float th0 = (pe[0] + pe[2]) * k36;             // quadrant 0 (rows 0-5, cols 0-5)
    float th1 = (pe[1] + pe[3]) * k36;             // quadrant 1 (rows 0-5, cols 6-11)
    float th2 = (pe[4] + pe[6]) * k36;             // quadrant 2
    float th3 = (pe[5] + pe[7]) * k36;             // quadrant 3

    float c0 = __cosf(th0), s0 = __sinf(th0);
    float c1 = __cosf(th1), s1 = __sinf(th1);
    float c2 = __cosf(th2), s2 = __sinf(th2);
    float c3 = __cosf(th3), s3 = __sinf(th3);

    // a[k] = product over qubits 0..3, qubit0 = MSB of k
    float u[4] = { c0 * c1, c0 * s1, s0 * c1, s0 * s1 };
    float v[4] = { c2 * c3, c2 * s3, s2 * c3, s2 * s3 };
    float a[16];
    #pragma unroll
    for (int i = 0; i < 4; ++i)
        #pragma unroll
        for (int jj = 0; jj < 4; ++jj) a[i * 4 + jj] = u[i] * v[jj];

    // out_p = a^T R_p a + b_p   (R via wave-uniform scalar loads)
    const float* Rp = R_ws + p * 256;
    float o = bvec[p];
    #pragma unroll
    for (int kk = 0; kk < 16; ++kk) {
        float dot = 0.f;
        #pragma unroll
        for (int ll = 0; ll < 16; ++ll) dot = fmaf(Rp[kk * 16 + ll], a[ll], dot);
        o = fmaf(a[kk], dot, o);
    }

    out_col[(size_t)p * B + blk * 64 + e] = o;

    // ---- per-wave reduction for BN stats (all lanes share p) ----
    float s1v = o, s2v = o * o;
    #pragma unroll
    for (int off = 1; off < 64; off <<= 1) {
        s1v += __shfl_xor(s1v, off);
        s2v += __shfl_xor(s2v, off);
    }
    if (e == 0) {
        const int bin = blk & 31;
        atomicAdd(&acc[bin * 8 + p],     (double)s1v);
        atomicAdd(&acc[bin * 8 + 4 + p], (double)s2v);
    }
}

// ---------------------------------------------------------------------------
// Kernel B: finalize batch-norm and write output [B][4].
// ---------------------------------------------------------------------------
__global__ __launch_bounds__(256) void bn_kernel(
    const float* __restrict__ out_col,  // [4][B]
    const double* __restrict__ acc,     // [32][8]
    const float* __restrict__ gamma,
    const float* __restrict__ beta,
    float* __restrict__ outp,           // [B][4]
    int B)
{
    __shared__ float sc[4], sh[4];
    const int t = threadIdx.x;
    if (t < 4) {
        double s = 0.0, s2 = 0.0;
        #pragma unroll
        for (int bin = 0; bin < 32; ++bin) {
            s  += acc[bin * 8 + t];
            s2 += acc[bin * 8 + 4 + t];
        }
        double invB = 1.0 / (double)B;
        double mean = s * invB;
        double var  = s2 * invB - mean * mean;
        float inv   = (float)(1.0 / sqrt(var + 1e-5));
        float g     = gamma[t] * inv;
        sc[t] = g;
        sh[t] = beta[t] - (float)mean * g;
    }
    __syncthreads();

    const int i = blockIdx.x * 256 + t;
    float o0 = out_col[(size_t)0 * B + i];
    float o1 = out_col[(size_t)1 * B + i];
    float o2 = out_col[(size_t)2 * B + i];
    float o3 = out_col[(size_t)3 * B + i];
    float4 r;
    r.x = fmaf(o0, sc[0], sh[0]);
    r.y = fmaf(o1, sc[1], sh[1]);
    r.z = fmaf(o2, sc[2], sh[2]);
    r.w = fmaf(o3, sc[3], sh[3]);
    ((float4*)outp)[i] = r;
}

// ---------------------------------------------------------------------------
extern "C" void kernel_launch(void* const* d_in, const int* in_sizes, int n_in,
                              void* d_out, int out_size, void* d_ws, size_t ws_size,
                              hipStream_t stream)
{
    const float* x      = (const float*)d_in[0];   // [B,1,12,12]
    const float* params = (const float*)d_in[1];   // [3,8]
    const float* W      = (const float*)d_in[2];   // [4,8]
    const float* bvec   = (const float*)d_in[3];   // [4]
    const float* gamma  = (const float*)d_in[4];   // [4]
    const float* beta   = (const float*)d_in[5];   // [4]

    const int B = in_sizes[0] / 144;               // 65536

    float*  R_ws    = (float*)d_ws;                           // 4 KB
    double* acc     = (double*)((char*)d_ws + 4096);          // 2 KB
    float*  out_col = (float*)((char*)d_ws + 8192);           // 4*B floats

    float* outp = (float*)d_out;

    setup_kernel<<<4, 256, 0, stream>>>(params, W, R_ws, acc);
    main_kernel<<<B / 64, 256, 0, stream>>>(x, bvec, R_ws, out_col, acc, B);
    bn_kernel<<<B / 256, 256, 0, stream>>>(out_col, acc, gamma, beta, outp, B);
}

// Round 4
// 101.822 us; speedup vs baseline: 1.1005x; 1.0199x over previous
//
#include <hip/hip_runtime.h>
#include <math.h>

#define NQ 8
#define NS 256      // 2^NQ amplitudes
#define NK 16       // encoded subspace (qubits 0-3)
#define NL 3
#define XS 20       // exchange-buffer row stride in words
#define MTS 260     // transposed row stride in words (16B aligned; 65 float4s)

// ---------------------------------------------------------------------------
// Kernel S: 4 blocks (one per output column j). Register-resident gate sim:
//  - layer 1 computed analytically (tensor-product closed form, no LDS)
//  - CNOT_n folded into layer n+1's q0+q1 gates: one 4-way LDS exchange
//  - CNOT_3 folded into the transpose write (inverse-Gray index)
//  - R_j[k][l] via 2x2 register-tiled LDS dot products, s-split across waves
// Block 0 additionally zeroes the BN accumulator bins.
// ---------------------------------------------------------------------------
__global__ __launch_bounds__(256) void setup_kernel(
    const float* __restrict__ params,   // [3][8]
    const float* __restrict__ W,        // [4][8]
    float* __restrict__ R_ws,           // [4][256]  (j, k*16+l)
    double* __restrict__ acc)           // [32][8]
{
    __shared__ float X[NS * XS];      // 20 KB exchange buffer (reused for partials)
    __shared__ float MT[NK * MTS];    // MT[k][s]  16.6 KB
    __shared__ float PT[NK * MTS];    // PT[k][s] = ts*M  16.6 KB
    const int t = threadIdx.x;
    const int j = blockIdx.x;

    if (j == 0) acc[t] = 0.0;   // zero BN accumulator bins (32 x 8 doubles)

    // all 24 gate angles (uniform -> scalar loads; kept in regs via full unroll)
    float cs[NL * NQ], sn[NL * NQ];
    #pragma unroll
    for (int i = 0; i < NL * NQ; ++i) {
        float th = params[i] * 0.5f;
        cs[i] = __cosf(th);
        sn[i] = __sinf(th);
    }

    // ---- layer 1: analytic (state t, basis column k) ----
    // column k starts as |k> on qubits 0-3 (bit (3-q) of k = qubit q), |0> on 4-7
    float m[NK];
    {
        float h = 1.f;
        #pragma unroll
        for (int q = 4; q < 8; ++q) {
            int z = (t >> (7 - q)) & 1;
            h *= z ? sn[q] : cs[q];
        }
        float v[4][2];
        #pragma unroll
        for (int q = 0; q < 4; ++q) {
            int z = (t >> (7 - q)) & 1;
            v[q][0] = z ? sn[q] : cs[q];    // initial |0>
            v[q][1] = z ? cs[q] : -sn[q];   // initial |1>
        }
        float p01[4], p23[4];
        #pragma unroll
        for (int b0 = 0; b0 < 2; ++b0)
            #pragma unroll
            for (int b1 = 0; b1 < 2; ++b1) {
                p01[b0 * 2 + b1] = v[0][b0] * v[1][b1];
                p23[b0 * 2 + b1] = v[2][b0] * v[3][b1];
            }
        #pragma unroll
        for (int k = 0; k < NK; ++k)
            m[k] = h * p01[k >> 2] * p23[k & 3];
    }

    // ---- layers 2,3: one LDS trip folds prev-CNOT + q0 + q1; then shfl gates ----
    #pragma unroll
    for (int ly = 1; ly < NL; ++ly) {
        if (ly > 1) __syncthreads();          // protect X from previous trip's reads
        #pragma unroll
        for (int k = 0; k < NK; k += 4)
            *(float4*)&X[t * XS + k] = make_float4(m[k], m[k+1], m[k+2], m[k+3]);
        __syncthreads();

        const int low = t & 63;
        float st[4][NK];
        #pragma unroll
        for (int i = 0; i < 2; ++i)
            #pragma unroll
            for (int jj = 0; jj < 2; ++jj) {
                int y  = (i << 7) | (jj << 6) | low;
                int sy = y ^ (y >> 1);        // CNOT chain permutation (Gray encode)
                #pragma unroll
                for (int k = 0; k < NK; k += 4) {
                    float4 vv = *(const float4*)&X[sy * XS + k];
                    st[i*2+jj][k]   = vv.x; st[i*2+jj][k+1] = vv.y;
                    st[i*2+jj][k+2] = vv.z; st[i*2+jj][k+3] = vv.w;
                }
            }

        const int z7 = (t >> 7) & 1, z6 = (t >> 6) & 1;
        const float c0 = cs[ly*8+0], s0 = sn[ly*8+0];
        const float c1 = cs[ly*8+1], s1 = sn[ly*8+1];
        float u0[2], u1[2];
        u0[0] = z7 ? s0 : c0;   u0[1] = z7 ? c0 : -s0;
        u1[0] = z6 ? s1 : c1;   u1[1] = z6 ? c1 : -s1;
        const float w00 = u0[0]*u1[0], w01 = u0[0]*u1[1];
        const float w10 = u0[1]*u1[0], w11 = u0[1]*u1[1];
        #pragma unroll
        for (int k = 0; k < NK; ++k)
            m[k] = w00*st[0][k] + w01*st[1][k] + w10*st[2][k] + w11*st[3][k];

        // in-wave gates q=2..7 (mask <= 32)
        #pragma unroll
        for (int q = 2; q < NQ; ++q) {
            const float c = cs[ly*8+q], s = sn[ly*8+q];
            const int mask = 1 << (7 - q);
            const float ss = (t & mask) ? s : -s;
            #pragma unroll
            for (int k = 0; k < NK; ++k) {
                float p = __shfl_xor(m[k], mask);
                m[k] = fmaf(ss, p, c * m[k]);
            }
        }
    }

    // ---- CNOT_3 folded into transpose: final index d = inverse-Gray(t) ----
    int d = t;
    d ^= d >> 1; d ^= d >> 2; d ^= d >> 4;    // prefix-XOR (8-bit Gray decode)

    float ts = 0.f;                            // ts_j evaluated at final index d
    #pragma unroll
    for (int w = 0; w < 8; ++w) {
        float sign = ((d >> (7 - w)) & 1) ? -1.f : 1.f;
        ts += W[j * 8 + w] * sign;
    }
    #pragma unroll
    for (int k = 0; k < NK; ++k) {
        MT[k * MTS + d] = m[k];
        PT[k * MTS + d] = ts * m[k];
    }
    __syncthreads();

    // ---- R reduction: 2x2 register tiles, wave w covers s in [64w, 64w+64) ----
    {
        const int w  = t >> 6;
        const int ln = t & 63;
        const int kk = ln >> 3, ll = ln & 7;
        const float4* A0 = (const float4*)&MT[(2*kk)     * MTS] + w * 16;
        const float4* A1 = (const float4*)&MT[(2*kk + 1) * MTS] + w * 16;
        const float4* B0 = (const float4*)&PT[(2*ll)     * MTS] + w * 16;
        const float4* B1 = (const float4*)&PT[(2*ll + 1) * MTS] + w * 16;
        float r00 = 0.f, r01 = 0.f, r10 = 0.f, r11 = 0.f;
        #pragma unroll
        for (int i = 0; i < 16; ++i) {
            float4 a0 = A0[i], a1 = A1[i], b0 = B0[i], b1 = B1[i];
            r00 = fmaf(a0.x,b0.x, fmaf(a0.y,b0.y, fmaf(a0.z,b0.z, fmaf(a0.w,b0.w, r00))));
            r01 = fmaf(a0.x,b1.x, fmaf(a0.y,b1.y, fmaf(a0.z,b1.z, fmaf(a0.w,b1.w, r01))));
            r10 = fmaf(a1.x,b0.x, fmaf(a1.y,b0.y, fmaf(a1.z,b0.z, fmaf(a1.w,b0.w, r10))));
            r11 = fmaf(a1.x,b1.x, fmaf(a1.y,b1.y, fmaf(a1.z,b1.z, fmaf(a1.w,b1.w, r11))));
        }
        // per-wave partials into X (X's last readers were ordered by the sync above)
        X[w * 256 + (2*kk)    *16 + 2*ll]     = r00;
        X[w * 256 + (2*kk)    *16 + 2*ll + 1] = r01;
        X[w * 256 + (2*kk + 1)*16 + 2*ll]     = r10;
        X[w * 256 + (2*kk + 1)*16 + 2*ll + 1] = r11;
        __syncthreads();
        R_ws[j * 256 + t] = X[t] + X[256 + t] + X[512 + t] + X[768 + t];
    }
}

// ---------------------------------------------------------------------------
// Kernel A: pooling + quadratic forms + BN partial sums.
// Block: 256 threads, 64 batch elements. Grid: B/64 blocks.
// ---------------------------------------------------------------------------
__global__ __launch_bounds__(256, 4) void main_kernel(
    const float* __restrict__ x,      // [B][144]
    const float* __restrict__ bvec,   // [4]
    const float* __restrict__ R_ws,   // [4][256]
    float* __restrict__ out_col,      // [4][B]  column-major pre-BN output
    double* __restrict__ acc,         // [32][8]
    int B)
{
    __shared__ float4 tile[2304];     // 64 elements * 36 float4 = 36 KB
    __shared__ float  part[64 * 9];   // per-(element, band-part) L/R sums, pad 9

    const int t   = threadIdx.x;
    const int blk = blockIdx.x;

    // ---- stage 64 elements (coalesced float4) ----
    const float4* xg = (const float4*)x + (size_t)blk * 2304;
    #pragma unroll
    for (int i = 0; i < 9; ++i) tile[i * 256 + t] = xg[i * 256 + t];
    __syncthreads();

    // ---- pooling partial sums: thread = (e = t>>2, p = t&3), p = 3-row band ----
    {
        float sl = 0.f, sr = 0.f;
        #pragma unroll
        for (int i = 0; i < 9; ++i) {
            float4 v = tile[t * 9 + i];
            const int mod = i % 3;      // position within a 12-col row
            if (mod == 0)      { sl += v.x + v.y + v.z + v.w; }
            else if (mod == 1) { sl += v.x + v.y; sr += v.z + v.w; }
            else               { sr += v.x + v.y + v.z + v.w; }
        }
        part[(t >> 2) * 9 + (t & 3) * 2 + 0] = sl;
        part[(t >> 2) * 9 + (t & 3) * 2 + 1] = sr;
    }
    __syncthreads();

    // ---- quadratic forms: wave w handles output column p = w for 64 elements ----
    const int e = t & 63;
    const int p = __builtin_amdgcn_readfirstlane(t >> 6);   // wave-uniform column

    const float* pe = &part[e * 9];
    const float k36 = 0.5f / 36.f;                 // mean + theta/2 folded
    float th0 = (pe[0] + pe[2]) * k36;             // quadrant 0 (rows 0-5, cols 0-5)
    float th1 = (pe[1] + pe[3]) * k36;             // quadrant 1 (rows 0-5, cols 6-11)
    float th2 = (pe[4] + pe[6]) * k36;             // quadrant 2
    float th3 = (pe[5] + pe[7]) * k36;             // quadrant 3

    float c0 = __cosf(th0), s0 = __sinf(th0);
    float c1 = __cosf(th1), s1 = __sinf(th1);
    float c2 = __cosf(th2), s2 = __sinf(th2);
    float c3 = __cosf(th3), s3 = __sinf(th3);

    // a[k] = product over qubits 0..3, qubit0 = MSB of k
    float u[4] = { c0 * c1, c0 * s1, s0 * c1, s0 * s1 };
    float v[4] = { c2 * c3, c2 * s3, s2 * c3, s2 * s3 };
    float a[16];
    #pragma unroll
    for (int i = 0; i < 4; ++i)
        #pragma unroll
        for (int jj = 0; jj < 4; ++jj) a[i * 4 + jj] = u[i] * v[jj];

    // out_p = a^T R_p a + b_p   (R via wave-uniform scalar loads)
    const float* Rp = R_ws + p * 256;
    float o = bvec[p];
    #pragma unroll
    for (int kk = 0; kk < 16; ++kk) {
        float dot = 0.f;
        #pragma unroll
        for (int ll = 0; ll < 16; ++ll) dot = fmaf(Rp[kk * 16 + ll], a[ll], dot);
        o = fmaf(a[kk], dot, o);
    }

    out_col[(size_t)p * B + blk * 64 + e] = o;

    // ---- per-wave reduction for BN stats (all lanes share p) ----
    float s1v = o, s2v = o * o;
    #pragma unroll
    for (int off = 1; off < 64; off <<= 1) {
        s1v += __shfl_xor(s1v, off);
        s2v += __shfl_xor(s2v, off);
    }
    if (e == 0) {
        const int bin = blk & 31;
        atomicAdd(&acc[bin * 8 + p],     (double)s1v);
        atomicAdd(&acc[bin * 8 + 4 + p], (double)s2v);
    }
}

// ---------------------------------------------------------------------------
// Kernel B: finalize batch-norm and write output [B][4].
// ---------------------------------------------------------------------------
__global__ __launch_bounds__(256) void bn_kernel(
    const float* __restrict__ out_col,  // [4][B]
    const double* __restrict__ acc,     // [32][8]
    const float* __restrict__ gamma,
    const float* __restrict__ beta,
    float* __restrict__ outp,           // [B][4]
    int B)
{
    __shared__ float sc[4], sh[4];
    const int t = threadIdx.x;
    if (t < 4) {
        double s = 0.0, s2 = 0.0;
        #pragma unroll
        for (int bin = 0; bin < 32; ++bin) {
            s  += acc[bin * 8 + t];
            s2 += acc[bin * 8 + 4 + t];
        }
        double invB = 1.0 / (double)B;
        double mean = s * invB;
        double var  = s2 * invB - mean * mean;
        float inv   = (float)(1.0 / sqrt(var + 1e-5));
        float g     = gamma[t] * inv;
        sc[t] = g;
        sh[t] = beta[t] - (float)mean * g;
    }
    __syncthreads();

    const int i = blockIdx.x * 256 + t;
    float o0 = out_col[(size_t)0 * B + i];
    float o1 = out_col[(size_t)1 * B + i];
    float o2 = out_col[(size_t)2 * B + i];
    float o3 = out_col[(size_t)3 * B + i];
    float4 r;
    r.x = fmaf(o0, sc[0], sh[0]);
    r.y = fmaf(o1, sc[1], sh[1]);
    r.z = fmaf(o2, sc[2], sh[2]);
    r.w = fmaf(o3, sc[3], sh[3]);
    ((float4*)outp)[i] = r;
}

// ---------------------------------------------------------------------------
extern "C" void kernel_launch(void* const* d_in, const int* in_sizes, int n_in,
                              void* d_out, int out_size, void* d_ws, size_t ws_size,
                              hipStream_t stream)
{
    const float* x      = (const float*)d_in[0];   // [B,1,12,12]
    const float* params = (const float*)d_in[1];   // [3,8]
    const float* W      = (const float*)d_in[2];   // [4,8]
    const float* bvec   = (const float*)d_in[3];   // [4]
    const float* gamma  = (const float*)d_in[4];   // [4]
    const float* beta   = (const float*)d_in[5];   // [4]

    const int B = in_sizes[0] / 144;               // 65536

    float*  R_ws    = (float*)d_ws;                           // 4 KB
    double* acc     = (double*)((char*)d_ws + 4096);          // 2 KB
    float*  out_col = (float*)((char*)d_ws + 8192);           // 4*B floats

    float* outp = (float*)d_out;

    setup_kernel<<<4, 256, 0, stream>>>(params, W, R_ws, acc);
    main_kernel<<<B / 64, 256, 0, stream>>>(x, bvec, R_ws, out_col, acc, B);
    bn_kernel<<<B / 256, 256, 0, stream>>>(out_col, acc, gamma, beta, outp, B);
}

// Round 7
// 101.652 us; speedup vs baseline: 1.1024x; 1.0017x over previous
//
#include <hip/hip_runtime.h>
#include <math.h>

#define NQ 8
#define NS 256      // 2^NQ amplitudes
#define NK 16       // encoded subspace (qubits 0-3)
#define NL 3
#define XS 20       // exchange-buffer row stride in words
#define MTS 260     // transposed row stride in words (16B aligned; 65 float4s)

// ---------------------------------------------------------------------------
// Kernel S: 4 blocks (one per output column j). Register-resident gate sim:
//  - layer 1 computed analytically (tensor-product closed form, no LDS)
//  - CNOT_n folded into layer n+1's q0+q1 gates: one 4-way LDS exchange
//  - CNOT_3 folded into the transpose write (inverse-Gray index)
//  - R_j[k][l] via 2x2 register-tiled LDS dot products, s-split across waves
// Block 0 additionally zeroes the BN accumulator bins.
// ---------------------------------------------------------------------------
__global__ __launch_bounds__(256) void setup_kernel(
    const float* __restrict__ params,   // [3][8]
    const float* __restrict__ W,        // [4][8]
    float* __restrict__ R_ws,           // [4][256]  (j, k*16+l)
    double* __restrict__ acc)           // [32][8]
{
    __shared__ float X[NS * XS];      // 20 KB exchange buffer (reused for partials)
    __shared__ float MT[NK * MTS];    // MT[k][s]  16.6 KB
    __shared__ float PT[NK * MTS];    // PT[k][s] = ts*M  16.6 KB
    const int t = threadIdx.x;
    const int j = blockIdx.x;

    if (j == 0) acc[t] = 0.0;   // zero BN accumulator bins (32 x 8 doubles)

    // all 24 gate angles (uniform -> scalar loads; kept in regs via full unroll)
    float cs[NL * NQ], sn[NL * NQ];
    #pragma unroll
    for (int i = 0; i < NL * NQ; ++i) {
        float th = params[i] * 0.5f;
        cs[i] = __cosf(th);
        sn[i] = __sinf(th);
    }

    // ---- layer 1: analytic (state t, basis column k) ----
    float m[NK];
    {
        float h = 1.f;
        #pragma unroll
        for (int q = 4; q < 8; ++q) {
            int z = (t >> (7 - q)) & 1;
            h *= z ? sn[q] : cs[q];
        }
        float v[4][2];
        #pragma unroll
        for (int q = 0; q < 4; ++q) {
            int z = (t >> (7 - q)) & 1;
            v[q][0] = z ? sn[q] : cs[q];    // initial |0>
            v[q][1] = z ? cs[q] : -sn[q];   // initial |1>
        }
        float p01[4], p23[4];
        #pragma unroll
        for (int b0 = 0; b0 < 2; ++b0)
            #pragma unroll
            for (int b1 = 0; b1 < 2; ++b1) {
                p01[b0 * 2 + b1] = v[0][b0] * v[1][b1];
                p23[b0 * 2 + b1] = v[2][b0] * v[3][b1];
            }
        #pragma unroll
        for (int k = 0; k < NK; ++k)
            m[k] = h * p01[k >> 2] * p23[k & 3];
    }

    // ---- layers 2,3: one LDS trip folds prev-CNOT + q0 + q1; then shfl gates ----
    #pragma unroll
    for (int ly = 1; ly < NL; ++ly) {
        if (ly > 1) __syncthreads();
        #pragma unroll
        for (int k = 0; k < NK; k += 4)
            *(float4*)&X[t * XS + k] = make_float4(m[k], m[k+1], m[k+2], m[k+3]);
        __syncthreads();

        const int low = t & 63;
        float st[4][NK];
        #pragma unroll
        for (int i = 0; i < 2; ++i)
            #pragma unroll
            for (int jj = 0; jj < 2; ++jj) {
                int y  = (i << 7) | (jj << 6) | low;
                int sy = y ^ (y >> 1);        // CNOT chain permutation (Gray encode)
                #pragma unroll
                for (int k = 0; k < NK; k += 4) {
                    float4 vv = *(const float4*)&X[sy * XS + k];
                    st[i*2+jj][k]   = vv.x; st[i*2+jj][k+1] = vv.y;
                    st[i*2+jj][k+2] = vv.z; st[i*2+jj][k+3] = vv.w;
                }
            }

        const int z7 = (t >> 7) & 1, z6 = (t >> 6) & 1;
        const float c0 = cs[ly*8+0], s0 = sn[ly*8+0];
        const float c1 = cs[ly*8+1], s1 = sn[ly*8+1];
        float u0[2], u1[2];
        u0[0] = z7 ? s0 : c0;   u0[1] = z7 ? c0 : -s0;
        u1[0] = z6 ? s1 : c1;   u1[1] = z6 ? c1 : -s1;
        const float w00 = u0[0]*u1[0], w01 = u0[0]*u1[1];
        const float w10 = u0[1]*u1[0], w11 = u0[1]*u1[1];
        #pragma unroll
        for (int k = 0; k < NK; ++k)
            m[k] = w00*st[0][k] + w01*st[1][k] + w10*st[2][k] + w11*st[3][k];

        // in-wave gates q=2..7 (mask <= 32)
        #pragma unroll
        for (int q = 2; q < NQ; ++q) {
            const float c = cs[ly*8+q], s = sn[ly*8+q];
            const int mask = 1 << (7 - q);
            const float ss = (t & mask) ? s : -s;
            #pragma unroll
            for (int k = 0; k < NK; ++k) {
                float p = __shfl_xor(m[k], mask);
                m[k] = fmaf(ss, p, c * m[k]);
            }
        }
    }

    // ---- CNOT_3 folded into transpose: final index d = inverse-Gray(t) ----
    int d = t;
    d ^= d >> 1; d ^= d >> 2; d ^= d >> 4;    // prefix-XOR (8-bit Gray decode)

    float ts = 0.f;                            // ts_j evaluated at final index d
    #pragma unroll
    for (int w = 0; w < 8; ++w) {
        float sign = ((d >> (7 - w)) & 1) ? -1.f : 1.f;
        ts += W[j * 8 + w] * sign;
    }
    #pragma unroll
    for (int k = 0; k < NK; ++k) {
        MT[k * MTS + d] = m[k];
        PT[k * MTS + d] = ts * m[k];
    }
    __syncthreads();

    // ---- R reduction: 2x2 register tiles, wave w covers s in [64w, 64w+64) ----
    {
        const int w  = t >> 6;
        const int ln = t & 63;
        const int kk = ln >> 3, ll = ln & 7;
        const float4* A0 = (const float4*)&MT[(2*kk)     * MTS] + w * 16;
        const float4* A1 = (const float4*)&MT[(2*kk + 1) * MTS] + w * 16;
        const float4* B0 = (const float4*)&PT[(2*ll)     * MTS] + w * 16;
        const float4* B1 = (const float4*)&PT[(2*ll + 1) * MTS] + w * 16;
        float r00 = 0.f, r01 = 0.f, r10 = 0.f, r11 = 0.f;
        #pragma unroll
        for (int i = 0; i < 16; ++i) {
            float4 a0 = A0[i], a1 = A1[i], b0 = B0[i], b1 = B1[i];
            r00 = fmaf(a0.x,b0.x, fmaf(a0.y,b0.y, fmaf(a0.z,b0.z, fmaf(a0.w,b0.w, r00))));
            r01 = fmaf(a0.x,b1.x, fmaf(a0.y,b1.y, fmaf(a0.z,b1.z, fmaf(a0.w,b1.w, r01))));
            r10 = fmaf(a1.x,b0.x, fmaf(a1.y,b0.y, fmaf(a1.z,b0.z, fmaf(a1.w,b0.w, r10))));
            r11 = fmaf(a1.x,b1.x, fmaf(a1.y,b1.y, fmaf(a1.z,b1.z, fmaf(a1.w,b1.w, r11))));
        }
        // per-wave partials into X (X's last readers were ordered by the sync above)
        X[w * 256 + (2*kk)    *16 + 2*ll]     = r00;
        X[w * 256 + (2*kk)    *16 + 2*ll + 1] = r01;
        X[w * 256 + (2*kk + 1)*16 + 2*ll]     = r10;
        X[w * 256 + (2*kk + 1)*16 + 2*ll + 1] = r11;
        __syncthreads();
        R_ws[j * 256 + t] = X[t] + X[256 + t] + X[512 + t] + X[768 + t];
    }
}

// ---------------------------------------------------------------------------
// Kernel A: pooling + quadratic forms + BN partial sums.
// Block: 256 threads, 64 batch elements. Grid: B/64 blocks.
// ---------------------------------------------------------------------------
__global__ __launch_bounds__(256, 4) void main_kernel(
    const float* __restrict__ x,      // [B][144]
    const float* __restrict__ bvec,   // [4]
    const float* __restrict__ R_ws,   // [4][256]
    float* __restrict__ out_col,      // [4][B]  column-major pre-BN output
    double* __restrict__ acc,         // [32][8]
    int B)
{
    __shared__ float4 tile[2304];     // 64 elements * 36 float4 = 36 KB
    __shared__ float  part[64 * 9];   // per-(element, band-part) L/R sums, pad 9

    const int t   = threadIdx.x;
    const int blk = blockIdx.x;

    // ---- stage 64 elements (coalesced float4) ----
    const float4* xg = (const float4*)x + (size_t)blk * 2304;
    #pragma unroll
    for (int i = 0; i < 9; ++i) tile[i * 256 + t] = xg[i * 256 + t];
    __syncthreads();

    // ---- pooling partial sums: thread = (e = t>>2, band p = t&3) ----
    {
        float sl = 0.f, sr = 0.f;
        #pragma unroll
        for (int i = 0; i < 9; ++i) {
            float4 v = tile[t * 9 + i];
            const int mod = i % 3;      // position within a 12-col row
            if (mod == 0)      { sl += v.x + v.y + v.z + v.w; }
            else if (mod == 1) { sl += v.x + v.y; sr += v.z + v.w; }
            else               { sr += v.x + v.y + v.z + v.w; }
        }
        part[(t >> 2) * 9 + (t & 3) * 2 + 0] = sl;
        part[(t >> 2) * 9 + (t & 3) * 2 + 1] = sr;
    }
    __syncthreads();

    // ---- quadratic forms: wave w handles output column p = w for 64 elements ----
    const int e = t & 63;
    const int p = __builtin_amdgcn_readfirstlane(t >> 6);   // wave-uniform column

    const float* pe = &part[e * 9];
    const float k36 = 0.5f / 36.f;                 // mean + theta/2 folded
    float th0 = (pe[0] + pe[2]) * k36;
    float th1 = (pe[1] + pe[3]) * k36;
    float th2 = (pe[4] + pe[6]) * k36;
    float th3 = (pe[5] + pe[7]) * k36;

    float c0 = __cosf(th0), s0 = __sinf(th0);
    float c1 = __cosf(th1), s1 = __sinf(th1);
    float c2 = __cosf(th2), s2 = __sinf(th2);
    float c3 = __cosf(th3), s3 = __sinf(th3);

    float u[4] = { c0 * c1, c0 * s1, s0 * c1, s0 * s1 };
    float v[4] = { c2 * c3, c2 * s3, s2 * c3, s2 * s3 };
    float a[16];
    #pragma unroll
    for (int i = 0; i < 4; ++i)
        #pragma unroll
        for (int jj = 0; jj < 4; ++jj) a[i * 4 + jj] = u[i] * v[jj];

    // out_p = a^T R_p a + b_p   (R via wave-uniform scalar loads)
    const float* Rp = R_ws + p * 256;
    float o = bvec[p];
    #pragma unroll
    for (int kk = 0; kk < 16; ++kk) {
        float dot = 0.f;
        #pragma unroll
        for (int ll = 0; ll < 16; ++ll) dot = fmaf(Rp[kk * 16 + ll], a[ll], dot);
        o = fmaf(a[kk], dot, o);
    }

    out_col[(size_t)p * B + blk * 64 + e] = o;

    // ---- per-wave reduction for BN stats (all lanes share p) ----
    float s1v = o, s2v = o * o;
    #pragma unroll
    for (int off = 1; off < 64; off <<= 1) {
        s1v += __shfl_xor(s1v, off);
        s2v += __shfl_xor(s2v, off);
    }
    if (e == 0) {
        const int bin = blk & 31;
        atomicAdd(&acc[bin * 8 + p],     (double)s1v);
        atomicAdd(&acc[bin * 8 + 4 + p], (double)s2v);
    }
}

// ---------------------------------------------------------------------------
// Kernel B: finalize batch-norm and write output [B][4].
// ---------------------------------------------------------------------------
__global__ __launch_bounds__(256) void bn_kernel(
    const float* __restrict__ out_col,  // [4][B]
    const double* __restrict__ acc,     // [32][8]
    const float* __restrict__ gamma,
    const float* __restrict__ beta,
    float* __restrict__ outp,           // [B][4]
    int B)
{
    __shared__ float sc[4], sh[4];
    const int t = threadIdx.x;
    if (t < 4) {
        double s = 0.0, s2 = 0.0;
        #pragma unroll
        for (int bin = 0; bin < 32; ++bin) {
            s  += acc[bin * 8 + t];
            s2 += acc[bin * 8 + 4 + t];
        }
        double invB = 1.0 / (double)B;
        double mean = s * invB;
        double var  = s2 * invB - mean * mean;
        float inv   = (float)(1.0 / sqrt(var + 1e-5));
        float g     = gamma[t] * inv;
        sc[t] = g;
        sh[t] = beta[t] - (float)mean * g;
    }
    __syncthreads();

    const int i = blockIdx.x * 256 + t;
    float o0 = out_col[(size_t)0 * B + i];
    float o1 = out_col[(size_t)1 * B + i];
    float o2 = out_col[(size_t)2 * B + i];
    float o3 = out_col[(size_t)3 * B + i];
    float4 r;
    r.x = fmaf(o0, sc[0], sh[0]);
    r.y = fmaf(o1, sc[1], sh[1]);
    r.z = fmaf(o2, sc[2], sh[2]);
    r.w = fmaf(o3, sc[3], sh[3]);
    ((float4*)outp)[i] = r;
}

// ---------------------------------------------------------------------------
extern "C" void kernel_launch(void* const* d_in, const int* in_sizes, int n_in,
                              void* d_out, int out_size, void* d_ws, size_t ws_size,
                              hipStream_t stream)
{
    const float* x      = (const float*)d_in[0];   // [B,1,12,12]
    const float* params = (const float*)d_in[1];   // [3,8]
    const float* W      = (const float*)d_in[2];   // [4,8]
    const float* bvec   = (const float*)d_in[3];   // [4]
    const float* gamma  = (const float*)d_in[4];   // [4]
    const float* beta   = (const float*)d_in[5];   // [4]

    const int B = in_sizes[0] / 144;               // 65536

    float*  R_ws    = (float*)d_ws;                           // 4 KB
    double* acc     = (double*)((char*)d_ws + 4096);          // 2 KB
    float*  out_col = (float*)((char*)d_ws + 8192);           // 4*B floats

    float* outp = (float*)d_out;

    setup_kernel<<<4, 256, 0, stream>>>(params, W, R_ws, acc);
    main_kernel<<<B / 64, 256, 0, stream>>>(x, bvec, R_ws, out_col, acc, B);
    bn_kernel<<<B / 256, 256, 0, stream>>>(out_col, acc, gamma, beta, outp, B);
}